// Round 2
// baseline (3396.425 us; speedup 1.0000x reference)
//
#include <hip/hip_runtime.h>
#include <hip/hip_bf16.h>

#define T_STEPS 256
#define BATCH   64
#define DIM_I   256
#define DIM_H   256
#define NBR     8
#define F_DIM   1024

typedef __attribute__((ext_vector_type(8))) short short8;
typedef __attribute__((ext_vector_type(4))) float floatx4;

// workspace layout (bytes)
#define WX_OFF  0u                  // 4 MB  bf16 W_x fragments [n][ks8][ct64][lane64][8]
#define WH_OFF  (4u<<20)            // 4 MB  bf16 W_h fragments [n][ks8][ct64][lane64][8]
#define C_OFF   (8u<<20)            // 512 KB fp32 c carry  [n][rt][tid512][8]
#define H_OFF   ((8u<<20) + 0x80000u) // 256 KB bf16 h carry [n][rt][row16][col256]
#define ZX_OFF  (16u<<20)           // CT * 2 MB fp32 z_x fragments [tt][n][rt][ct][lane][4]

__device__ __forceinline__ float sigmoid_fast(float x) {
    return 1.0f / (1.0f + __expf(-x));
}
__device__ __forceinline__ float tanh_fast(float x) {
    return 1.0f - 2.0f / (__expf(2.0f * x) + 1.0f);
}
// fp32 -> bf16 bits, round-to-nearest-even (finite inputs only)
__device__ __forceinline__ short f2bf(float f) {
    unsigned u = __float_as_uint(f);
    u += 0x7FFFu + ((u >> 16) & 1u);
    return (short)(u >> 16);
}

// ---------------------------------------------------------------------------
// Kernel 1: convert weight fp32 [N][512][1024] -> bf16 B-fragment order,
// split into W_x (k<256) and W_h (k>=256).
// Fragment layout: [n][ks][ct][lane][j], lane = qr*16 + c0, where for global k:
// ks=(k&255)>>5, qr=(k>>3)&3, j=k&7; ct=f>>4, c0=f&15.
// ---------------------------------------------------------------------------
__global__ void __launch_bounds__(256)
prep_kernel(const float* __restrict__ weight, short* __restrict__ wx,
            short* __restrict__ wh) {
    int id = blockIdx.x * 256 + threadIdx.x;     // 8*512*1024 = 4194304 total
    int f  = id & 1023;
    int kk = (id >> 10) & 511;
    int n  = id >> 19;
    float v = weight[(size_t)id];                // [n][kk][f] contiguous == id
    int ks = (kk & 255) >> 5;
    int qr = (kk >> 3) & 3;
    int j  = kk & 7;
    int ct = f >> 4;
    int c0 = f & 15;
    int lane = qr * 16 + c0;
    size_t o = ((((size_t)n * 8 + ks) * 64 + ct) * 64 + lane) * 8 + j;
    (kk < 256 ? wx : wh)[o] = f2bf(v);
}

// ---------------------------------------------------------------------------
// Kernel 2: z_x[tt][n][m][ct][lane][0..3] = x[t] @ W_x[n] + bias  (fp32, D-frag
// order). Grid CT*8 blocks (n = bid&7 for XCD locality of W_x[n]), 256 thr.
// Wave w covers coltiles w*16..w*16+15, all 4 row-subtiles (64 batch rows).
// ---------------------------------------------------------------------------
__global__ void __launch_bounds__(256)
xgemm_kernel(const float* __restrict__ x, const short* __restrict__ wxg,
             const float* __restrict__ bias_i, const float* __restrict__ bias_h,
             floatx4* __restrict__ zx, int t0) {
    const int tid = threadIdx.x;
    const int lane = tid & 63, w = tid >> 6;
    const int l15 = lane & 15, quad = lane >> 4;
    const int n = blockIdx.x & 7;
    const int tt = blockIdx.x >> 3;
    const int t = t0 + tt;

    const short8* wx8 = (const short8*)wxg + (size_t)n * 8 * 64 * 64;

    // A fragments: 4 row-subtiles x 8 k-steps, bf16 from fp32 x
    short8 a[4][8];
#pragma unroll
    for (int m = 0; m < 4; ++m) {
        const float* xr = x + ((size_t)t * BATCH + m * 16 + l15) * DIM_I + quad * 8;
#pragma unroll
        for (int ks = 0; ks < 8; ++ks) {
            const floatx4* p = (const floatx4*)(xr + ks * 32);
            floatx4 u = p[0], v = p[1];
            short8 af;
            af[0] = f2bf(u[0]); af[1] = f2bf(u[1]); af[2] = f2bf(u[2]); af[3] = f2bf(u[3]);
            af[4] = f2bf(v[0]); af[5] = f2bf(v[1]); af[6] = f2bf(v[2]); af[7] = f2bf(v[3]);
            a[m][ks] = af;
        }
    }

    for (int ci = 0; ci < 16; ++ci) {
        const int ct = w * 16 + ci;
        float bb = bias_i[n * F_DIM + ct * 16 + l15] + bias_h[n * F_DIM + ct * 16 + l15];
        short8 bw[8];
#pragma unroll
        for (int ks = 0; ks < 8; ++ks)
            bw[ks] = wx8[(ks * 64 + ct) * 64 + lane];
#pragma unroll
        for (int m = 0; m < 4; ++m) {
            floatx4 acc = (floatx4){bb, bb, bb, bb};
#pragma unroll
            for (int ks = 0; ks < 8; ++ks)
                acc = __builtin_amdgcn_mfma_f32_16x16x32_bf16(a[m][ks], bw[ks], acc, 0, 0, 0);
            zx[((((size_t)tt * 8 + n) * 4 + m) * 64 + ct) * 64 + lane] = acc;
        }
    }
}

// ---------------------------------------------------------------------------
// Kernel 3: recurrence. 32 blocks (n = bid&7, rt = bid>>3 -> 16 batch rows),
// 512 threads = 8 waves; wave w owns h-cols w*32..w*32+31 (coltiles
// ct = nt*16 + w*2 + q for gates nt=0..3, so the LSTM epilogue is lane-local).
//
// W_h is FULLY register-resident: wr[8ks][8ci] = 256 VGPR/lane. The per-step
// inner loop has ZERO weight traffic -- only the z_x/dur prefetch for step
// t+1 (a full step of latency slack). h ping-pongs in LDS with XOR-swizzle
// (byte ^= (row&7)<<4, 512B row stride) making ds_read_b128 bank-conflict-
// free. t-loop unrolled x2 with named pfA/pfB so the MFMA accumulator IS the
// prefetch register (no per-step copy, no runtime-indexed arrays).
// ---------------------------------------------------------------------------
__global__ void __launch_bounds__(512, 2)
rec_kernel(const floatx4* __restrict__ zx, const int* __restrict__ dur,
           const short* __restrict__ whg, float* __restrict__ out,
           float* __restrict__ c_carry, short* __restrict__ h_carry,
           int t0, int CT) {
    __shared__ short hlds[2][16 * 256];   // 2 x 8 KB, XOR-swizzled rows

    const int tid = threadIdx.x;
    const int lane = tid & 63, w = tid >> 6;
    const int l15 = lane & 15, quad = lane >> 4;
    const int n = blockIdx.x & 7;
    const int rt = blockIdx.x >> 3;
    const int r0 = rt * 16;

    const short8* wh8 = (const short8*)whg + (size_t)n * 8 * 64 * 64;
    const int swz = (l15 & 7) << 4;       // A-read swizzle (row = l15)
    char* h0 = (char*)&hlds[0][0];
    char* h1 = (char*)&hlds[1][0];

    // ---- load h carry into hlds[0] (swizzled; zeroed by host at t=0) ----
    {
        const short8* src = (const short8*)(h_carry + ((size_t)n * 4 + rt) * 4096);
        int row = tid >> 5, cg = tid & 31;
        *(short8*)(h0 + row * 512 + ((cg * 16) ^ ((row & 7) << 4))) = src[tid];
    }
    // ---- load c carry ----
    float c[2][4];
    {
        const float* cp = c_carry + (((size_t)n * 4 + rt) * 512 + tid) * 8;
#pragma unroll
        for (int q = 0; q < 2; ++q)
#pragma unroll
            for (int r = 0; r < 4; ++r) c[q][r] = cp[q * 4 + r];
    }
    // ---- W_h fully register-resident: 8 ks x 8 coltiles = 256 VGPR ----
    short8 wr[8][8];
#pragma unroll
    for (int ks = 0; ks < 8; ++ks)
#pragma unroll
        for (int ci = 0; ci < 8; ++ci) {
            const int ct = (ci >> 1) * 16 + w * 2 + (ci & 1);
            wr[ks][ci] = wh8[(ks * 64 + ct) * 64 + lane];
        }

    // ---- initial prefetch: z_x(tt=0) + dur(t0) ----
    const size_t zxb = (size_t)(n * 4 + rt) * 4096 + lane;
    floatx4 pfA[8], pfB[8];
    int4 dA, dB;
#pragma unroll
    for (int ci = 0; ci < 8; ++ci) {
        const int ct = (ci >> 1) * 16 + w * 2 + (ci & 1);
        pfA[ci] = zx[zxb + ct * 64];
    }
    dA = *(const int4*)(dur + (size_t)t0 * BATCH + r0 + quad * 4);

    __syncthreads();  // hlds[0] ready

#define STEP(TT, HC, HN, PFC, PFN, DC, DN)                                     \
    {                                                                          \
        const int t_ = t0 + (TT);                                              \
        /* A fragments from swizzled LDS (bank-conflict-free ds_read_b128) */  \
        short8 a_[8];                                                          \
        _Pragma("unroll")                                                      \
        for (int ks = 0; ks < 8; ++ks)                                         \
            a_[ks] = *(const short8*)((HC) + l15 * 512 +                       \
                                      ((ks * 64 + quad * 16) ^ swz));          \
        /* prefetch next step's z_x + dur (hidden under MFMA + epilogue) */    \
        const int ttn_ = ((TT) + 1 < CT) ? (TT) + 1 : (TT);                    \
        _Pragma("unroll")                                                      \
        for (int ci = 0; ci < 8; ++ci) {                                       \
            const int ct_ = (ci >> 1) * 16 + w * 2 + (ci & 1);                 \
            (PFN)[ci] = zx[(size_t)ttn_ * 131072 + zxb + ct_ * 64];            \
        }                                                                      \
        (DN) = *(const int4*)(dur + (size_t)(t0 + ttn_) * BATCH + r0 + quad * 4); \
        /* MFMA: accumulate into PFC (z_x + bias preloaded) */                 \
        _Pragma("unroll")                                                      \
        for (int ci = 0; ci < 8; ++ci) {                                       \
            _Pragma("unroll")                                                  \
            for (int ks = 0; ks < 8; ++ks)                                     \
                (PFC)[ci] = __builtin_amdgcn_mfma_f32_16x16x32_bf16(           \
                    a_[ks], wr[ks][ci], (PFC)[ci], 0, 0, 0);                   \
        }                                                                      \
        /* pointwise LSTM epilogue: lane-local */                              \
        const int dv_[4] = {(DC).x, (DC).y, (DC).z, (DC).w};                   \
        _Pragma("unroll")                                                      \
        for (int r = 0; r < 4; ++r) {                                          \
            const bool freeze = n > (dv_[r] >> 3);                             \
            const int row = quad * 4 + r;                                      \
            _Pragma("unroll")                                                  \
            for (int q = 0; q < 2; ++q) {                                      \
                float zi = (PFC)[0 + q][r];                                    \
                float zf = (PFC)[2 + q][r];                                    \
                float zo = (PFC)[4 + q][r];                                    \
                float zg = (PFC)[6 + q][r];                                    \
                float ig = sigmoid_fast(zi);                                   \
                float fg = sigmoid_fast(zf);                                   \
                float og = sigmoid_fast(zo);                                   \
                float gg = tanh_fast(zg);                                      \
                float cn = freeze ? c[q][r] : fg * c[q][r] + ig * gg;          \
                c[q][r] = cn;                                                  \
                float hv = og * tanh_fast(cn);                                 \
                const int hcol = w * 32 + q * 16 + l15;                        \
                out[(((size_t)t_ * NBR + n) * BATCH + (r0 + row)) * DIM_H + hcol] = hv; \
                *(short*)((HN) + row * 512 + ((2 * hcol) ^ ((row & 7) << 4))) = f2bf(hv); \
            }                                                                  \
        }                                                                      \
    }

    for (int tt = 0; tt < CT; tt += 2) {
        STEP(tt,     h0, h1, pfA, pfB, dA, dB);
        __syncthreads();
        STEP(tt + 1, h1, h0, pfB, pfA, dB, dA);
        __syncthreads();
    }
#undef STEP

    // ---- store carries for next chunk (CT even -> final h is in hlds[0]) ----
    {
        float* cp = c_carry + (((size_t)n * 4 + rt) * 512 + tid) * 8;
#pragma unroll
        for (int q = 0; q < 2; ++q)
#pragma unroll
            for (int r = 0; r < 4; ++r) cp[q * 4 + r] = c[q][r];
        int row = tid >> 5, cg = tid & 31;
        short8 v = *(const short8*)(h0 + row * 512 + ((cg * 16) ^ ((row & 7) << 4)));
        ((short8*)(h_carry + ((size_t)n * 4 + rt) * 4096))[tid] = v;
    }
}

extern "C" void kernel_launch(void* const* d_in, const int* in_sizes, int n_in,
                              void* d_out, int out_size, void* d_ws, size_t ws_size,
                              hipStream_t stream) {
    const float* x      = (const float*)d_in[0];
    const int*   durp   = (const int*)d_in[1];
    const float* weight = (const float*)d_in[2];
    const float* bias_i = (const float*)d_in[3];
    const float* bias_h = (const float*)d_in[4];
    float* out = (float*)d_out;
    char*  ws  = (char*)d_ws;

    short*   wx      = (short*)(ws + WX_OFF);
    short*   wh      = (short*)(ws + WH_OFF);
    float*   c_carry = (float*)(ws + C_OFF);
    short*   h_carry = (short*)(ws + H_OFF);
    floatx4* zxp     = (floatx4*)(ws + ZX_OFF);

    // pick largest T-chunk whose z_x buffer fits the workspace (2 MB / step)
    int CT = 256;
    while (CT > 2 && (size_t)ZX_OFF + (size_t)CT * 2097152ull > ws_size) CT >>= 1;

    // zero h/c carries (t=0 state)
    hipMemsetAsync(ws + C_OFF, 0, 524288 + 262144, stream);

    // weight repack: fp32 -> bf16 fragments
    prep_kernel<<<16384, 256, 0, stream>>>(weight, wx, wh);

    for (int t0 = 0; t0 < T_STEPS; t0 += CT) {
        xgemm_kernel<<<CT * 8, 256, 0, stream>>>(x, wx, bias_i, bias_h, zxp, t0);
        rec_kernel<<<32, 512, 0, stream>>>(zxp, durp, wh, out, c_carry, h_carry, t0, CT);
    }
}

// Round 3
// 2660.705 us; speedup vs baseline: 1.2765x; 1.2765x over previous
//
#include <hip/hip_runtime.h>
#include <hip/hip_bf16.h>

#define T_STEPS 256
#define BATCH   64
#define DIM_I   256
#define DIM_H   256
#define NBR     8
#define F_DIM   1024

typedef __attribute__((ext_vector_type(8))) short short8;
typedef __attribute__((ext_vector_type(4))) float floatx4;

// workspace layout (bytes)
#define WX_OFF  0u                  // 4 MB  bf16 W_x fragments [n][ks8][ct64][lane64][8]
#define WH_OFF  (4u<<20)            // 4 MB  bf16 W_h fragments [n][ks8][ct64][lane64][8]
#define C_OFF   (8u<<20)            // 512 KB fp32 c carry  [n][rt][tid512][8]
#define H_OFF   ((8u<<20) + 0x80000u) // 256 KB bf16 h carry [n][rt][row16][col256]
#define ZX_OFF  (16u<<20)           // CT * 2 MB fp32 z_x fragments [tt][n][rt][ct][lane][4]

__device__ __forceinline__ float sigmoid_fast(float x) {
    return 1.0f / (1.0f + __expf(-x));
}
__device__ __forceinline__ float tanh_fast(float x) {
    return 1.0f - 2.0f / (__expf(2.0f * x) + 1.0f);
}
// fp32 -> bf16 bits, round-to-nearest-even (finite inputs only)
__device__ __forceinline__ short f2bf(float f) {
    unsigned u = __float_as_uint(f);
    u += 0x7FFFu + ((u >> 16) & 1u);
    return (short)(u >> 16);
}

// ---------------------------------------------------------------------------
// Kernel 1: convert weight fp32 [N][512][1024] -> bf16 B-fragment order,
// split into W_x (k<256) and W_h (k>=256).
// Fragment layout: [n][ks][ct][lane][j], lane = qr*16 + c0, where for global k:
// ks=(k&255)>>5, qr=(k>>3)&3, j=k&7; ct=f>>4, c0=f&15.
// ---------------------------------------------------------------------------
__global__ void __launch_bounds__(256)
prep_kernel(const float* __restrict__ weight, short* __restrict__ wx,
            short* __restrict__ wh) {
    int id = blockIdx.x * 256 + threadIdx.x;     // 8*512*1024 = 4194304 total
    int f  = id & 1023;
    int kk = (id >> 10) & 511;
    int n  = id >> 19;
    float v = weight[(size_t)id];                // [n][kk][f] contiguous == id
    int ks = (kk & 255) >> 5;
    int qr = (kk >> 3) & 3;
    int j  = kk & 7;
    int ct = f >> 4;
    int c0 = f & 15;
    int lane = qr * 16 + c0;
    size_t o = ((((size_t)n * 8 + ks) * 64 + ct) * 64 + lane) * 8 + j;
    (kk < 256 ? wx : wh)[o] = f2bf(v);
}

// ---------------------------------------------------------------------------
// Kernel 2: z_x[tt][n][m][ct][lane][0..3] = x[t] @ W_x[n] + bias  (fp32, D-frag
// order). Grid CT*8 blocks (n = bid&7 for XCD locality of W_x[n]), 256 thr.
// ---------------------------------------------------------------------------
__global__ void __launch_bounds__(256)
xgemm_kernel(const float* __restrict__ x, const short* __restrict__ wxg,
             const float* __restrict__ bias_i, const float* __restrict__ bias_h,
             floatx4* __restrict__ zx, int t0) {
    const int tid = threadIdx.x;
    const int lane = tid & 63, w = tid >> 6;
    const int l15 = lane & 15, quad = lane >> 4;
    const int n = blockIdx.x & 7;
    const int tt = blockIdx.x >> 3;
    const int t = t0 + tt;

    const short8* wx8 = (const short8*)wxg + (size_t)n * 8 * 64 * 64;

    short8 a[4][8];
#pragma unroll
    for (int m = 0; m < 4; ++m) {
        const float* xr = x + ((size_t)t * BATCH + m * 16 + l15) * DIM_I + quad * 8;
#pragma unroll
        for (int ks = 0; ks < 8; ++ks) {
            const floatx4* p = (const floatx4*)(xr + ks * 32);
            floatx4 u = p[0], v = p[1];
            short8 af;
            af[0] = f2bf(u[0]); af[1] = f2bf(u[1]); af[2] = f2bf(u[2]); af[3] = f2bf(u[3]);
            af[4] = f2bf(v[0]); af[5] = f2bf(v[1]); af[6] = f2bf(v[2]); af[7] = f2bf(v[3]);
            a[m][ks] = af;
        }
    }

    for (int ci = 0; ci < 16; ++ci) {
        const int ct = w * 16 + ci;
        float bb = bias_i[n * F_DIM + ct * 16 + l15] + bias_h[n * F_DIM + ct * 16 + l15];
        short8 bw[8];
#pragma unroll
        for (int ks = 0; ks < 8; ++ks)
            bw[ks] = wx8[(ks * 64 + ct) * 64 + lane];
#pragma unroll
        for (int m = 0; m < 4; ++m) {
            floatx4 acc = (floatx4){bb, bb, bb, bb};
#pragma unroll
            for (int ks = 0; ks < 8; ++ks)
                acc = __builtin_amdgcn_mfma_f32_16x16x32_bf16(a[m][ks], bw[ks], acc, 0, 0, 0);
            zx[((((size_t)tt * 8 + n) * 4 + m) * 64 + ct) * 64 + lane] = acc;
        }
    }
}

// ---------------------------------------------------------------------------
// Kernel 3: recurrence. 32 blocks (n = bid&7, rt = bid>>3), 512 threads =
// 8 waves; wave w owns coltiles ct = nt*16 + w*2 + q (gate nt=ci>>1, q=ci&1)
// so the LSTM epilogue is lane-local.
//
// W_h residency (sized to FIT the 256-VGPR budget; round-2's full-reg pin
// spilled because launch_bounds min-waves let the allocator target 128):
//   regs : ks0..2  -> wr[3][8]  (96 VGPR)
//   LDS  : ks3,4   -> wl, 128 KB wave-private fragments (conflict-free b128)
//   L2   : ks5..7  -> sb[4][3] depth-4 rotation; consume sb[ci&3], refill it
//          for ci+4 (mod 8). W addresses are step-invariant, so the stream
//          pipeline never drains -- ~12 loads/wave in flight continuously.
// acc is single-buffered: reloaded from z_x at the end of each step
// (accumulation order zx-first + ks ascending == previous rounds, so
// numerics are bit-identical). amdgpu_waves_per_eu(2,2) pins the allocator
// at 2 waves/EU -> full 256-VGPR budget, no spill incentive.
// ---------------------------------------------------------------------------
__global__ __attribute__((amdgpu_flat_work_group_size(512, 512),
                          amdgpu_waves_per_eu(2, 2)))
void rec_kernel(const floatx4* __restrict__ zx, const int* __restrict__ dur,
                const short* __restrict__ whg, float* __restrict__ out,
                float* __restrict__ c_carry, short* __restrict__ h_carry,
                int t0, int CT) {
    __shared__ short hlds[2][16 * 256];   // 16 KB h ping-pong, XOR-swizzled
    __shared__ short wl[2 * 8 * 8 * 512]; // 128 KB: [ksl2*8+ci][w][512]

    const int tid = threadIdx.x;
    const int lane = tid & 63, w = tid >> 6;
    const int l15 = lane & 15, quad = lane >> 4;
    const int n = blockIdx.x & 7;
    const int rt = blockIdx.x >> 3;
    const int r0 = rt * 16;

    const short8* wh8 = (const short8*)whg + (size_t)n * 8 * 64 * 64;
    const int swz = (l15 & 7) << 4;       // A-read swizzle (row = l15)
    char* h0 = (char*)&hlds[0][0];
    char* h1 = (char*)&hlds[1][0];

    // ---- h carry -> hlds[0] (swizzled; zeroed by host at t=0) ----
    {
        const short8* src = (const short8*)(h_carry + ((size_t)n * 4 + rt) * 4096);
        int row = tid >> 5, cg = tid & 31;
        *(short8*)(h0 + row * 512 + ((cg * 16) ^ ((row & 7) << 4))) = src[tid];
    }
    // ---- c carry ----
    float c[2][4];
    {
        const float* cp = c_carry + (((size_t)n * 4 + rt) * 512 + tid) * 8;
#pragma unroll
        for (int q = 0; q < 2; ++q)
#pragma unroll
            for (int r = 0; r < 4; ++r) c[q][r] = cp[q * 4 + r];
    }
    // ---- LDS-pinned W ks3,4 (wave-private fragment regions) ----
#pragma unroll
    for (int idx = 0; idx < 16; ++idx) {
        const int ci = idx & 7;
        const int ksl = idx >> 3;                       // 0 -> ks3, 1 -> ks4
        const int ct = (ci >> 1) * 16 + w * 2 + (ci & 1);
        short8 v = wh8[((ksl + 3) * 64 + ct) * 64 + lane];
        *(short8*)(&wl[((size_t)idx * 8 + w) * 512 + lane * 8]) = v;
    }
    // ---- reg-pinned W ks0..2 (96 VGPR) ----
    short8 wr[3][8];
#pragma unroll
    for (int ks = 0; ks < 3; ++ks)
#pragma unroll
        for (int ci = 0; ci < 8; ++ci) {
            const int ct = (ci >> 1) * 16 + w * 2 + (ci & 1);
            wr[ks][ci] = wh8[(ks * 64 + ct) * 64 + lane];
        }
    // ---- stream prologue: ks5..7 for ci 0..3 (depth-4 pipeline fill) ----
    short8 sb[4][3];
#pragma unroll
    for (int ci = 0; ci < 4; ++ci) {
        const int ct = (ci >> 1) * 16 + w * 2 + (ci & 1);
#pragma unroll
        for (int s = 0; s < 3; ++s)
            sb[ci][s] = wh8[((s + 5) * 64 + ct) * 64 + lane];
    }
    // ---- acc init = z_x(tt=0); dur(t0) ----
    const size_t zxb = (size_t)(n * 4 + rt) * 4096 + lane;
    floatx4 acc[8];
#pragma unroll
    for (int ci = 0; ci < 8; ++ci) {
        const int ct = (ci >> 1) * 16 + w * 2 + (ci & 1);
        acc[ci] = zx[zxb + ct * 64];
    }
    int4 dA = *(const int4*)(dur + (size_t)t0 * BATCH + r0 + quad * 4);
    int4 dB;

    __syncthreads();  // hlds[0] + wl ready

#define STEP(TT, HC, HN, DC, DN)                                               \
    {                                                                          \
        const int t_ = t0 + (TT);                                              \
        const int ttn_ = ((TT) + 1 < CT) ? (TT) + 1 : (TT);                    \
        /* A fragments from swizzled LDS (bank-conflict-free ds_read_b128) */  \
        short8 a_[8];                                                          \
        _Pragma("unroll")                                                      \
        for (int ks = 0; ks < 8; ++ks)                                         \
            a_[ks] = *(const short8*)((HC) + l15 * 512 +                       \
                                      ((ks * 64 + quad * 16) ^ swz));          \
        (DN) = *(const int4*)(dur + (size_t)(t0 + ttn_) * BATCH + r0 + quad * 4); \
        /* MFMA: ks0..2 reg, ks3..4 LDS, ks5..7 stream (ascending order) */    \
        _Pragma("unroll")                                                      \
        for (int ci = 0; ci < 8; ++ci) {                                       \
            acc[ci] = __builtin_amdgcn_mfma_f32_16x16x32_bf16(a_[0], wr[0][ci], acc[ci], 0, 0, 0); \
            acc[ci] = __builtin_amdgcn_mfma_f32_16x16x32_bf16(a_[1], wr[1][ci], acc[ci], 0, 0, 0); \
            acc[ci] = __builtin_amdgcn_mfma_f32_16x16x32_bf16(a_[2], wr[2][ci], acc[ci], 0, 0, 0); \
            short8 b3_ = *(const short8*)(&wl[((size_t)(0 * 8 + ci) * 8 + w) * 512 + lane * 8]); \
            acc[ci] = __builtin_amdgcn_mfma_f32_16x16x32_bf16(a_[3], b3_, acc[ci], 0, 0, 0); \
            short8 b4_ = *(const short8*)(&wl[((size_t)(1 * 8 + ci) * 8 + w) * 512 + lane * 8]); \
            acc[ci] = __builtin_amdgcn_mfma_f32_16x16x32_bf16(a_[4], b4_, acc[ci], 0, 0, 0); \
            acc[ci] = __builtin_amdgcn_mfma_f32_16x16x32_bf16(a_[5], sb[ci & 3][0], acc[ci], 0, 0, 0); \
            acc[ci] = __builtin_amdgcn_mfma_f32_16x16x32_bf16(a_[6], sb[ci & 3][1], acc[ci], 0, 0, 0); \
            acc[ci] = __builtin_amdgcn_mfma_f32_16x16x32_bf16(a_[7], sb[ci & 3][2], acc[ci], 0, 0, 0); \
            /* refill sb[ci&3] for ci+4 (mod 8): continuous, step-invariant */ \
            const int cin_ = (ci + 4) & 7;                                     \
            const int ctn_ = (cin_ >> 1) * 16 + w * 2 + (cin_ & 1);            \
            sb[ci & 3][0] = wh8[(5 * 64 + ctn_) * 64 + lane];                  \
            sb[ci & 3][1] = wh8[(6 * 64 + ctn_) * 64 + lane];                  \
            sb[ci & 3][2] = wh8[(7 * 64 + ctn_) * 64 + lane];                  \
        }                                                                      \
        /* pointwise LSTM epilogue: lane-local */                              \
        const int dv_[4] = {(DC).x, (DC).y, (DC).z, (DC).w};                   \
        _Pragma("unroll")                                                      \
        for (int r = 0; r < 4; ++r) {                                          \
            const bool freeze = n > (dv_[r] >> 3);                             \
            const int row = quad * 4 + r;                                      \
            _Pragma("unroll")                                                  \
            for (int q = 0; q < 2; ++q) {                                      \
                float zi = acc[0 + q][r];                                      \
                float zf = acc[2 + q][r];                                      \
                float zo = acc[4 + q][r];                                      \
                float zg = acc[6 + q][r];                                      \
                float ig = sigmoid_fast(zi);                                   \
                float fg = sigmoid_fast(zf);                                   \
                float og = sigmoid_fast(zo);                                   \
                float gg = tanh_fast(zg);                                      \
                float cn = freeze ? c[q][r] : fg * c[q][r] + ig * gg;          \
                c[q][r] = cn;                                                  \
                float hv = og * tanh_fast(cn);                                 \
                const int hcol = w * 32 + q * 16 + l15;                        \
                out[(((size_t)t_ * NBR + n) * BATCH + (r0 + row)) * DIM_H + hcol] = hv; \
                *(short*)((HN) + row * 512 + ((2 * hcol) ^ ((row & 7) << 4))) = f2bf(hv); \
            }                                                                  \
        }                                                                      \
        /* reload acc = z_x(t+1): barrier + next step's a-reads cover L2 */    \
        _Pragma("unroll")                                                      \
        for (int ci = 0; ci < 8; ++ci) {                                       \
            const int ct_ = (ci >> 1) * 16 + w * 2 + (ci & 1);                 \
            acc[ci] = zx[(size_t)ttn_ * 131072 + zxb + ct_ * 64];              \
        }                                                                      \
    }

    for (int tt = 0; tt < CT; tt += 2) {
        STEP(tt,     h0, h1, dA, dB);
        __syncthreads();
        STEP(tt + 1, h1, h0, dB, dA);
        __syncthreads();
    }
#undef STEP

    // ---- store carries for next chunk (CT even -> final h is in hlds[0]) ----
    {
        float* cp = c_carry + (((size_t)n * 4 + rt) * 512 + tid) * 8;
#pragma unroll
        for (int q = 0; q < 2; ++q)
#pragma unroll
            for (int r = 0; r < 4; ++r) cp[q * 4 + r] = c[q][r];
        int row = tid >> 5, cg = tid & 31;
        short8 v = *(const short8*)(h0 + row * 512 + ((cg * 16) ^ ((row & 7) << 4)));
        ((short8*)(h_carry + ((size_t)n * 4 + rt) * 4096))[tid] = v;
    }
}

extern "C" void kernel_launch(void* const* d_in, const int* in_sizes, int n_in,
                              void* d_out, int out_size, void* d_ws, size_t ws_size,
                              hipStream_t stream) {
    const float* x      = (const float*)d_in[0];
    const int*   durp   = (const int*)d_in[1];
    const float* weight = (const float*)d_in[2];
    const float* bias_i = (const float*)d_in[3];
    const float* bias_h = (const float*)d_in[4];
    float* out = (float*)d_out;
    char*  ws  = (char*)d_ws;

    short*   wx      = (short*)(ws + WX_OFF);
    short*   wh      = (short*)(ws + WH_OFF);
    float*   c_carry = (float*)(ws + C_OFF);
    short*   h_carry = (short*)(ws + H_OFF);
    floatx4* zxp     = (floatx4*)(ws + ZX_OFF);

    // pick largest T-chunk whose z_x buffer fits the workspace (2 MB / step)
    int CT = 256;
    while (CT > 2 && (size_t)ZX_OFF + (size_t)CT * 2097152ull > ws_size) CT >>= 1;

    // zero h/c carries (t=0 state)
    hipMemsetAsync(ws + C_OFF, 0, 524288 + 262144, stream);

    // weight repack: fp32 -> bf16 fragments
    prep_kernel<<<16384, 256, 0, stream>>>(weight, wx, wh);

    for (int t0 = 0; t0 < T_STEPS; t0 += CT) {
        xgemm_kernel<<<CT * 8, 256, 0, stream>>>(x, wx, bias_i, bias_h, zxp, t0);
        rec_kernel<<<32, 512, 0, stream>>>(zxp, durp, wh, out, c_carry, h_carry, t0, CT);
    }
}